// Round 1
// baseline (3297.852 us; speedup 1.0000x reference)
//
#include <hip/hip_runtime.h>
#include <hip/hip_bf16.h>

#define NEG_SLOPE 0.2f

// ---------------------------------------------------------------------------
// Fused dual GEMM: outl = act(x) @ Wl + bl ; outr = act(x) @ Wr + br
// x: [n,128], W: [128,128] row-major, out: [n,128]
// Block: 256 threads, 32 nodes per block. Each thread: 2 cols x 16 nodes for
// one of {Wl, Wr}. 128 FMA per 16 ds_read_b128 -> compute-bound.
// ---------------------------------------------------------------------------
template<bool RELU_IN>
__global__ __launch_bounds__(256)
void gemm_dual(const float* __restrict__ x,
               const float* __restrict__ Wl, const float* __restrict__ bl,
               const float* __restrict__ Wr, const float* __restrict__ br,
               float* __restrict__ outl, float* __restrict__ outr, int n)
{
    __shared__ float xs[32][128];
    const int tid = threadIdx.x;
    const int node0 = blockIdx.x * 32;

    // stage 32 x-rows into LDS (float4, coalesced), relu folded in if requested
    #pragma unroll
    for (int it = 0; it < 4; ++it) {
        int flat = (it * 256 + tid) * 4;   // 0..16380
        int row = flat >> 7;
        int col = flat & 127;
        float4 v = make_float4(0.f, 0.f, 0.f, 0.f);
        if (node0 + row < n) {
            v = *reinterpret_cast<const float4*>(&x[(size_t)(node0 + row) * 128 + col]);
            if (RELU_IN) {
                v.x = fmaxf(v.x, 0.f); v.y = fmaxf(v.y, 0.f);
                v.z = fmaxf(v.z, 0.f); v.w = fmaxf(v.w, 0.f);
            }
        }
        *reinterpret_cast<float4*>(&xs[row][col]) = v;
    }
    __syncthreads();

    const int jj   = (tid & 63) * 2;     // 2 consecutive output columns
    const int grp  = tid >> 6;           // 0..3
    const int matr = grp & 1;            // 0 -> Wl, 1 -> Wr
    const int nbase = (grp >> 1) * 16;   // node half

    const float* __restrict__ W    = matr ? Wr : Wl;
    const float* __restrict__ bias = matr ? br : bl;
    float* __restrict__ out        = matr ? outr : outl;

    float2 acc[16];
    #pragma unroll
    for (int i = 0; i < 16; ++i) acc[i] = make_float2(0.f, 0.f);

    for (int k0 = 0; k0 < 128; k0 += 4) {
        float2 w0 = *reinterpret_cast<const float2*>(&W[(k0 + 0) * 128 + jj]);
        float2 w1 = *reinterpret_cast<const float2*>(&W[(k0 + 1) * 128 + jj]);
        float2 w2 = *reinterpret_cast<const float2*>(&W[(k0 + 2) * 128 + jj]);
        float2 w3 = *reinterpret_cast<const float2*>(&W[(k0 + 3) * 128 + jj]);
        #pragma unroll
        for (int i = 0; i < 16; ++i) {
            float4 xv = *reinterpret_cast<const float4*>(&xs[nbase + i][k0]);
            acc[i].x = fmaf(xv.x, w0.x, acc[i].x);
            acc[i].y = fmaf(xv.x, w0.y, acc[i].y);
            acc[i].x = fmaf(xv.y, w1.x, acc[i].x);
            acc[i].y = fmaf(xv.y, w1.y, acc[i].y);
            acc[i].x = fmaf(xv.z, w2.x, acc[i].x);
            acc[i].y = fmaf(xv.z, w2.y, acc[i].y);
            acc[i].x = fmaf(xv.w, w3.x, acc[i].x);
            acc[i].y = fmaf(xv.w, w3.y, acc[i].y);
        }
    }

    const float2 b2 = make_float2(bias[jj], bias[jj + 1]);
    #pragma unroll
    for (int i = 0; i < 16; ++i) {
        int node = node0 + nbase + i;
        if (node < n) {
            float2 r = make_float2(acc[i].x + b2.x, acc[i].y + b2.y);
            *reinterpret_cast<float2*>(&out[(size_t)node * 128 + jj]) = r;
        }
    }
}

// ---------------------------------------------------------------------------
// init destination with per-column bias (out[n][j] = b[j]); total4 = n*32
// ---------------------------------------------------------------------------
__global__ __launch_bounds__(256)
void init_bias(float* __restrict__ out, const float* __restrict__ b, int total4)
{
    int idx = blockIdx.x * 256 + threadIdx.x;
    if (idx >= total4) return;
    int j = (idx & 31) * 4;   // (idx*4) % 128
    float4 bv = *reinterpret_cast<const float4*>(&b[j]);
    reinterpret_cast<float4*>(out)[idx] = bv;
}

// ---------------------------------------------------------------------------
// Score pass: 32 lanes per edge. score[e,h] = att[h,:] . lrelu(xl[s]+xr[d])
// ex = exp(score) (no max-subtract: scores are O(1), fp32 exp is exact enough
// and softmax is shift-invariant). atomicAdd into denom[d,h], store ex.
// ---------------------------------------------------------------------------
template<int H>
__global__ __launch_bounds__(256)
void score_kernel(const float* __restrict__ xl, const float* __restrict__ xr,
                  const float* __restrict__ att, const int* __restrict__ esrc,
                  const int* __restrict__ edst, int e_in, int e_tot,
                  float* __restrict__ exw, float* __restrict__ denom)
{
    int e = blockIdx.x * 8 + (threadIdx.x >> 5);
    if (e >= e_tot) return;
    int lane = threadIdx.x & 31;
    int s, d;
    if (e < e_in) { s = esrc[e]; d = edst[e]; } else { s = e - e_in; d = s; }

    float4 a  = *reinterpret_cast<const float4*>(&xl[(size_t)s * 128 + lane * 4]);
    float4 b  = *reinterpret_cast<const float4*>(&xr[(size_t)d * 128 + lane * 4]);
    float4 at = *reinterpret_cast<const float4*>(&att[lane * 4]);

    float4 t = make_float4(a.x + b.x, a.y + b.y, a.z + b.z, a.w + b.w);
    t.x = t.x > 0.f ? t.x : NEG_SLOPE * t.x;
    t.y = t.y > 0.f ? t.y : NEG_SLOPE * t.y;
    t.z = t.z > 0.f ? t.z : NEG_SLOPE * t.z;
    t.w = t.w > 0.f ? t.w : NEG_SLOPE * t.w;

    float p = t.x * at.x + t.y * at.y + t.z * at.z + t.w * at.w;
    p += __shfl_xor(p, 1);
    p += __shfl_xor(p, 2);
    p += __shfl_xor(p, 4);
    if (H == 1) {
        p += __shfl_xor(p, 8);
        p += __shfl_xor(p, 16);
    }
    float ex = __expf(p);

    if (H == 4) {
        if ((lane & 7) == 0) {
            int head = lane >> 3;
            exw[(size_t)e * 4 + head] = ex;
            atomicAdd(&denom[(size_t)d * 4 + head], ex);
        }
    } else {
        if (lane == 0) {
            exw[e] = ex;
            atomicAdd(&denom[d], ex);
        }
    }
}

// ---------------------------------------------------------------------------
// Aggregate pass: out[d] += xl[s] * alpha, alpha = ex/(denom[d]+1e-16)
// 32 lanes/edge, 4 atomicAdds per lane.
// ---------------------------------------------------------------------------
template<int H>
__global__ __launch_bounds__(256)
void agg_kernel(const float* __restrict__ xl, const int* __restrict__ esrc,
                const int* __restrict__ edst, const float* __restrict__ exw,
                const float* __restrict__ denom, int e_in, int e_tot,
                float* __restrict__ out)
{
    int e = blockIdx.x * 8 + (threadIdx.x >> 5);
    if (e >= e_tot) return;
    int lane = threadIdx.x & 31;
    int s, d;
    if (e < e_in) { s = esrc[e]; d = edst[e]; } else { s = e - e_in; d = s; }

    int head = (H == 4) ? (lane >> 3) : 0;
    float alpha = exw[(size_t)e * H + head] / (denom[(size_t)d * H + head] + 1e-16f);

    float4 v = *reinterpret_cast<const float4*>(&xl[(size_t)s * 128 + lane * 4]);
    float* o = &out[(size_t)d * 128 + lane * 4];
    atomicAdd(o + 0, v.x * alpha);
    atomicAdd(o + 1, v.y * alpha);
    atomicAdd(o + 2, v.z * alpha);
    atomicAdd(o + 3, v.w * alpha);
}

// ---------------------------------------------------------------------------

extern "C" void kernel_launch(void* const* d_in, const int* in_sizes, int n_in,
                              void* d_out, int out_size, void* d_ws, size_t ws_size,
                              hipStream_t stream)
{
    const int*   edge  = (const int*)d_in[0];
    const float* embed = (const float*)d_in[1];
    const float* Wl1   = (const float*)d_in[2];
    const float* bl1   = (const float*)d_in[3];
    const float* Wr1   = (const float*)d_in[4];
    const float* br1   = (const float*)d_in[5];
    const float* att1  = (const float*)d_in[6];
    const float* b1    = (const float*)d_in[7];
    const float* Wl2   = (const float*)d_in[8];
    const float* bl2   = (const float*)d_in[9];
    const float* Wr2   = (const float*)d_in[10];
    const float* br2   = (const float*)d_in[11];
    const float* att2  = (const float*)d_in[12];
    const float* b2    = (const float*)d_in[13];

    const int e_in  = in_sizes[0] / 2;
    const int n     = in_sizes[1] / 128;
    const int e_tot = e_in + n;

    float* ws     = (float*)d_ws;
    float* xl     = ws;                          // n*128
    float* xr     = xl + (size_t)n * 128;        // n*128
    float* h1     = xr + (size_t)n * 128;        // n*128
    float* exw    = h1 + (size_t)n * 128;        // e_tot*4 (layer2 uses e_tot*1)
    float* denom  = exw + (size_t)e_tot * 4;     // n*4  (layer 1)
    float* denom2 = denom + (size_t)n * 4;       // n    (layer 2)
    float* out    = (float*)d_out;

    const int* esrc = edge;
    const int* edst = edge + e_in;

    // zero both denominator buffers (adjacent)
    hipMemsetAsync(denom, 0, (size_t)(n * 4 + n) * sizeof(float), stream);

    dim3 blk(256);
    const int gemm_blocks = (n + 31) / 32;
    const int edge_blocks = (e_tot + 7) / 8;
    const int eltw_blocks = (n * 32 + 255) / 256;

    // ---- layer 1 (4 heads x 32 ch) ----
    gemm_dual<false><<<gemm_blocks, blk, 0, stream>>>(embed, Wl1, bl1, Wr1, br1, xl, xr, n);
    score_kernel<4><<<edge_blocks, blk, 0, stream>>>(xl, xr, att1, esrc, edst, e_in, e_tot, exw, denom);
    init_bias<<<eltw_blocks, blk, 0, stream>>>(h1, b1, n * 32);
    agg_kernel<4><<<edge_blocks, blk, 0, stream>>>(xl, esrc, edst, exw, denom, e_in, e_tot, h1);

    // ---- layer 2 (1 head x 128 ch); relu folded into GEMM x-load ----
    gemm_dual<true><<<gemm_blocks, blk, 0, stream>>>(h1, Wl2, bl2, Wr2, br2, xl, xr, n);
    score_kernel<1><<<edge_blocks, blk, 0, stream>>>(xl, xr, att2, esrc, edst, e_in, e_tot, exw, denom2);
    init_bias<<<eltw_blocks, blk, 0, stream>>>(out, b2, n * 32);
    agg_kernel<1><<<edge_blocks, blk, 0, stream>>>(xl, esrc, edst, exw, denom2, e_in, e_tot, out);
}

// Round 2
// 535.183 us; speedup vs baseline: 6.1621x; 6.1621x over previous
//
#include <hip/hip_runtime.h>
#include <hip/hip_bf16.h>

#define NEG_SLOPE 0.2f

// ---------------------------------------------------------------------------
// Fused dual GEMM: outl = act(x) @ Wl + bl ; outr = act(x) @ Wr + br
// x: [n,128], W: [128,128] row-major, out: [n,128]
// Block: 256 threads, 32 nodes per block. Each thread: 2 cols x 16 nodes for
// one of {Wl, Wr}.
// ---------------------------------------------------------------------------
template<bool RELU_IN>
__global__ __launch_bounds__(256)
void gemm_dual(const float* __restrict__ x,
               const float* __restrict__ Wl, const float* __restrict__ bl,
               const float* __restrict__ Wr, const float* __restrict__ br,
               float* __restrict__ outl, float* __restrict__ outr, int n)
{
    __shared__ float xs[32][128];
    const int tid = threadIdx.x;
    const int node0 = blockIdx.x * 32;

    #pragma unroll
    for (int it = 0; it < 4; ++it) {
        int flat = (it * 256 + tid) * 4;
        int row = flat >> 7;
        int col = flat & 127;
        float4 v = make_float4(0.f, 0.f, 0.f, 0.f);
        if (node0 + row < n) {
            v = *reinterpret_cast<const float4*>(&x[(size_t)(node0 + row) * 128 + col]);
            if (RELU_IN) {
                v.x = fmaxf(v.x, 0.f); v.y = fmaxf(v.y, 0.f);
                v.z = fmaxf(v.z, 0.f); v.w = fmaxf(v.w, 0.f);
            }
        }
        *reinterpret_cast<float4*>(&xs[row][col]) = v;
    }
    __syncthreads();

    const int jj   = (tid & 63) * 2;
    const int grp  = tid >> 6;
    const int matr = grp & 1;
    const int nbase = (grp >> 1) * 16;

    const float* __restrict__ W    = matr ? Wr : Wl;
    const float* __restrict__ bias = matr ? br : bl;
    float* __restrict__ out        = matr ? outr : outl;

    float2 acc[16];
    #pragma unroll
    for (int i = 0; i < 16; ++i) acc[i] = make_float2(0.f, 0.f);

    for (int k0 = 0; k0 < 128; k0 += 4) {
        float2 w0 = *reinterpret_cast<const float2*>(&W[(k0 + 0) * 128 + jj]);
        float2 w1 = *reinterpret_cast<const float2*>(&W[(k0 + 1) * 128 + jj]);
        float2 w2 = *reinterpret_cast<const float2*>(&W[(k0 + 2) * 128 + jj]);
        float2 w3 = *reinterpret_cast<const float2*>(&W[(k0 + 3) * 128 + jj]);
        #pragma unroll
        for (int i = 0; i < 16; ++i) {
            float4 xv = *reinterpret_cast<const float4*>(&xs[nbase + i][k0]);
            acc[i].x = fmaf(xv.x, w0.x, acc[i].x);
            acc[i].y = fmaf(xv.x, w0.y, acc[i].y);
            acc[i].x = fmaf(xv.y, w1.x, acc[i].x);
            acc[i].y = fmaf(xv.y, w1.y, acc[i].y);
            acc[i].x = fmaf(xv.z, w2.x, acc[i].x);
            acc[i].y = fmaf(xv.z, w2.y, acc[i].y);
            acc[i].x = fmaf(xv.w, w3.x, acc[i].x);
            acc[i].y = fmaf(xv.w, w3.y, acc[i].y);
        }
    }

    const float2 b2 = make_float2(bias[jj], bias[jj + 1]);
    #pragma unroll
    for (int i = 0; i < 16; ++i) {
        int node = node0 + nbase + i;
        if (node < n) {
            float2 r = make_float2(acc[i].x + b2.x, acc[i].y + b2.y);
            *reinterpret_cast<float2*>(&out[(size_t)node * 128 + jj]) = r;
        }
    }
}

// ---------------------------------------------------------------------------
// CSR build: degree init (=1 for the self loop), count, scan, scatter.
// ---------------------------------------------------------------------------
__global__ __launch_bounds__(256)
void deg_init(int* __restrict__ deg, int n)
{
    int i = blockIdx.x * 256 + threadIdx.x;
    if (i < n) deg[i] = 1;   // self loop contributes 1 incoming edge
}

__global__ __launch_bounds__(256)
void deg_count(const int* __restrict__ edst, int e_in, int* __restrict__ deg)
{
    int e = blockIdx.x * 256 + threadIdx.x;
    if (e < e_in) atomicAdd(&deg[edst[e]], 1);
}

#define SCAN_THREADS 1024
__global__ __launch_bounds__(SCAN_THREADS)
void scan_kernel(const int* __restrict__ deg, int* __restrict__ offsets,
                 int* __restrict__ cursor, int n)
{
    __shared__ int sums[SCAN_THREADS];
    const int t = threadIdx.x;
    const int chunk = (n + SCAN_THREADS - 1) / SCAN_THREADS;
    const int lo = t * chunk;
    const int hi = min(n, lo + chunk);
    int s = 0;
    for (int i = lo; i < hi; ++i) s += deg[i];
    sums[t] = s;
    __syncthreads();
    for (int off = 1; off < SCAN_THREADS; off <<= 1) {
        int v = (t >= off) ? sums[t - off] : 0;
        __syncthreads();
        sums[t] += v;
        __syncthreads();
    }
    int run = (t > 0) ? sums[t - 1] : 0;   // exclusive prefix
    for (int i = lo; i < hi; ++i) {
        offsets[i] = run;
        cursor[i]  = run;
        run += deg[i];
    }
    if (t == SCAN_THREADS - 1) offsets[n] = sums[SCAN_THREADS - 1];
}

__global__ __launch_bounds__(256)
void scatter_kernel(const int* __restrict__ esrc, const int* __restrict__ edst,
                    int e_in, int e_tot, int* __restrict__ cursor,
                    int* __restrict__ csr_src)
{
    int e = blockIdx.x * 256 + threadIdx.x;
    if (e >= e_tot) return;
    int s, d;
    if (e < e_in) { s = esrc[e]; d = edst[e]; } else { s = e - e_in; d = s; }
    int pos = atomicAdd(&cursor[d], 1);
    csr_src[pos] = s;
}

// ---------------------------------------------------------------------------
// Fused attention: one 32-lane group per destination node.
// For node d: loop over incoming edges (CSR), gather xl[s], compute
// score = att . lrelu(xl[s]+xr[d]) per head, ex = exp(score);
// accumulate den += ex, acc += xl[s]*ex. out[d] = acc/den + bias.
// No atomics, xl read once per edge, softmax normalization deferred.
// ---------------------------------------------------------------------------
template<int H>
__global__ __launch_bounds__(256)
void fused_attn(const float* __restrict__ xl, const float* __restrict__ xr,
                const float* __restrict__ att, const int* __restrict__ csr_src,
                const int* __restrict__ offsets, const float* __restrict__ bias,
                float* __restrict__ out, int n)
{
    int d = blockIdx.x * 8 + (threadIdx.x >> 5);
    if (d >= n) return;
    const int lane = threadIdx.x & 31;

    const float4 xrv = *reinterpret_cast<const float4*>(&xr[(size_t)d * 128 + lane * 4]);
    const float4 atv = *reinterpret_cast<const float4*>(&att[lane * 4]);

    const int start = offsets[d];
    const int end   = offsets[d + 1];

    float4 acc = make_float4(0.f, 0.f, 0.f, 0.f);
    float  den = 0.f;

    for (int base = start; base < end; base += 32) {
        const int cnt = min(32, end - base);
        int sidx = (base + lane < end) ? csr_src[base + lane] : 0;
        for (int i = 0; i < cnt; ++i) {
            int s = __shfl(sidx, i, 32);
            float4 xlv = *reinterpret_cast<const float4*>(&xl[(size_t)s * 128 + lane * 4]);
            float4 t = make_float4(xlv.x + xrv.x, xlv.y + xrv.y,
                                   xlv.z + xrv.z, xlv.w + xrv.w);
            t.x = t.x > 0.f ? t.x : NEG_SLOPE * t.x;
            t.y = t.y > 0.f ? t.y : NEG_SLOPE * t.y;
            t.z = t.z > 0.f ? t.z : NEG_SLOPE * t.z;
            t.w = t.w > 0.f ? t.w : NEG_SLOPE * t.w;
            float p = t.x * atv.x + t.y * atv.y + t.z * atv.z + t.w * atv.w;
            p += __shfl_xor(p, 1);
            p += __shfl_xor(p, 2);
            p += __shfl_xor(p, 4);
            if (H == 1) {
                p += __shfl_xor(p, 8);
                p += __shfl_xor(p, 16);
            }
            float ex = __expf(p);
            den += ex;
            acc.x = fmaf(xlv.x, ex, acc.x);
            acc.y = fmaf(xlv.y, ex, acc.y);
            acc.z = fmaf(xlv.z, ex, acc.z);
            acc.w = fmaf(xlv.w, ex, acc.w);
        }
    }

    const float inv = 1.f / (den + 1e-16f);
    const float4 bv = *reinterpret_cast<const float4*>(&bias[lane * 4]);
    float4 r = make_float4(acc.x * inv + bv.x, acc.y * inv + bv.y,
                           acc.z * inv + bv.z, acc.w * inv + bv.w);
    *reinterpret_cast<float4*>(&out[(size_t)d * 128 + lane * 4]) = r;
}

// ---------------------------------------------------------------------------

extern "C" void kernel_launch(void* const* d_in, const int* in_sizes, int n_in,
                              void* d_out, int out_size, void* d_ws, size_t ws_size,
                              hipStream_t stream)
{
    const int*   edge  = (const int*)d_in[0];
    const float* embed = (const float*)d_in[1];
    const float* Wl1   = (const float*)d_in[2];
    const float* bl1   = (const float*)d_in[3];
    const float* Wr1   = (const float*)d_in[4];
    const float* br1   = (const float*)d_in[5];
    const float* att1  = (const float*)d_in[6];
    const float* b1    = (const float*)d_in[7];
    const float* Wl2   = (const float*)d_in[8];
    const float* bl2   = (const float*)d_in[9];
    const float* Wr2   = (const float*)d_in[10];
    const float* br2   = (const float*)d_in[11];
    const float* att2  = (const float*)d_in[12];
    const float* b2    = (const float*)d_in[13];

    const int e_in  = in_sizes[0] / 2;
    const int n     = in_sizes[1] / 128;
    const int e_tot = e_in + n;

    float* ws   = (float*)d_ws;
    float* xl   = ws;                         // n*128 f
    float* xr   = xl + (size_t)n * 128;       // n*128 f
    float* h1   = xr + (size_t)n * 128;       // n*128 f
    int* csr_src = (int*)(h1 + (size_t)n * 128);  // e_tot int
    int* offsets = csr_src + e_tot;           // n+1 int
    int* cursor  = offsets + (n + 1);         // n int
    int* deg     = cursor + n;                // n int
    float* out   = (float*)d_out;

    const int* esrc = edge;
    const int* edst = edge + e_in;

    dim3 blk(256);
    const int gemm_blocks = (n + 31) / 32;
    const int node_blocks = (n + 7) / 8;

    // ---- CSR build (shared by both layers) ----
    deg_init<<<(n + 255) / 256, blk, 0, stream>>>(deg, n);
    deg_count<<<(e_in + 255) / 256, blk, 0, stream>>>(edst, e_in, deg);
    scan_kernel<<<1, SCAN_THREADS, 0, stream>>>(deg, offsets, cursor, n);
    scatter_kernel<<<(e_tot + 255) / 256, blk, 0, stream>>>(esrc, edst, e_in, e_tot, cursor, csr_src);

    // ---- layer 1 (4 heads x 32 ch) ----
    gemm_dual<false><<<gemm_blocks, blk, 0, stream>>>(embed, Wl1, bl1, Wr1, br1, xl, xr, n);
    fused_attn<4><<<node_blocks, blk, 0, stream>>>(xl, xr, att1, csr_src, offsets, b1, h1, n);

    // ---- layer 2 (1 head x 128 ch); relu folded into GEMM x-load ----
    gemm_dual<true><<<gemm_blocks, blk, 0, stream>>>(h1, Wl2, bl2, Wr2, br2, xl, xr, n);
    fused_attn<1><<<node_blocks, blk, 0, stream>>>(xl, xr, att2, csr_src, offsets, b2, out, n);
}

// Round 3
// 433.067 us; speedup vs baseline: 7.6151x; 1.2358x over previous
//
#include <hip/hip_runtime.h>
#include <hip/hip_bf16.h>

#define NEG_SLOPE 0.2f

// ---------------------------------------------------------------------------
// Fused dual GEMM: outl = act(x) @ Wl + bl ; outr = act(x) @ Wr + br
// ---------------------------------------------------------------------------
template<bool RELU_IN>
__global__ __launch_bounds__(256)
void gemm_dual(const float* __restrict__ x,
               const float* __restrict__ Wl, const float* __restrict__ bl,
               const float* __restrict__ Wr, const float* __restrict__ br,
               float* __restrict__ outl, float* __restrict__ outr, int n)
{
    __shared__ float xs[32][128];
    const int tid = threadIdx.x;
    const int node0 = blockIdx.x * 32;

    #pragma unroll
    for (int it = 0; it < 4; ++it) {
        int flat = (it * 256 + tid) * 4;
        int row = flat >> 7;
        int col = flat & 127;
        float4 v = make_float4(0.f, 0.f, 0.f, 0.f);
        if (node0 + row < n) {
            v = *reinterpret_cast<const float4*>(&x[(size_t)(node0 + row) * 128 + col]);
            if (RELU_IN) {
                v.x = fmaxf(v.x, 0.f); v.y = fmaxf(v.y, 0.f);
                v.z = fmaxf(v.z, 0.f); v.w = fmaxf(v.w, 0.f);
            }
        }
        *reinterpret_cast<float4*>(&xs[row][col]) = v;
    }
    __syncthreads();

    const int jj   = (tid & 63) * 2;
    const int grp  = tid >> 6;
    const int matr = grp & 1;
    const int nbase = (grp >> 1) * 16;

    const float* __restrict__ W    = matr ? Wr : Wl;
    const float* __restrict__ bias = matr ? br : bl;
    float* __restrict__ out        = matr ? outr : outl;

    float2 acc[16];
    #pragma unroll
    for (int i = 0; i < 16; ++i) acc[i] = make_float2(0.f, 0.f);

    for (int k0 = 0; k0 < 128; k0 += 4) {
        float2 w0 = *reinterpret_cast<const float2*>(&W[(k0 + 0) * 128 + jj]);
        float2 w1 = *reinterpret_cast<const float2*>(&W[(k0 + 1) * 128 + jj]);
        float2 w2 = *reinterpret_cast<const float2*>(&W[(k0 + 2) * 128 + jj]);
        float2 w3 = *reinterpret_cast<const float2*>(&W[(k0 + 3) * 128 + jj]);
        #pragma unroll
        for (int i = 0; i < 16; ++i) {
            float4 xv = *reinterpret_cast<const float4*>(&xs[nbase + i][k0]);
            acc[i].x = fmaf(xv.x, w0.x, acc[i].x);
            acc[i].y = fmaf(xv.x, w0.y, acc[i].y);
            acc[i].x = fmaf(xv.y, w1.x, acc[i].x);
            acc[i].y = fmaf(xv.y, w1.y, acc[i].y);
            acc[i].x = fmaf(xv.z, w2.x, acc[i].x);
            acc[i].y = fmaf(xv.z, w2.y, acc[i].y);
            acc[i].x = fmaf(xv.w, w3.x, acc[i].x);
            acc[i].y = fmaf(xv.w, w3.y, acc[i].y);
        }
    }

    const float2 b2 = make_float2(bias[jj], bias[jj + 1]);
    #pragma unroll
    for (int i = 0; i < 16; ++i) {
        int node = node0 + nbase + i;
        if (node < n) {
            float2 r = make_float2(acc[i].x + b2.x, acc[i].y + b2.y);
            *reinterpret_cast<float2*>(&out[(size_t)node * 128 + jj]) = r;
        }
    }
}

// ---------------------------------------------------------------------------
// CSR build.  deg zeroed via memset; deg_count handles real edges AND
// self loops in one dispatch.
// ---------------------------------------------------------------------------
__global__ __launch_bounds__(256)
void deg_count(const int* __restrict__ edst, int e_in, int e_tot,
               int* __restrict__ deg)
{
    int e = blockIdx.x * 256 + threadIdx.x;
    if (e >= e_tot) return;
    int d = (e < e_in) ? edst[e] : (e - e_in);
    atomicAdd(&deg[d], 1);
}

// --- 3-phase multi-block exclusive scan of deg[0..n) -> offsets/cursor -----
__global__ __launch_bounds__(256)
void scan_phase1(const int* __restrict__ deg, int* __restrict__ partials, int n)
{
    __shared__ int red[256];
    int i = blockIdx.x * 256 + threadIdx.x;
    int v = (i < n) ? deg[i] : 0;
    red[threadIdx.x] = v;
    __syncthreads();
    for (int off = 128; off > 0; off >>= 1) {
        if (threadIdx.x < off) red[threadIdx.x] += red[threadIdx.x + off];
        __syncthreads();
    }
    if (threadIdx.x == 0) partials[blockIdx.x] = red[0];
}

__global__ __launch_bounds__(1024)
void scan_phase2(int* __restrict__ partials, int nblocks)
{
    __shared__ int s[1024];
    int t = threadIdx.x;
    int v = (t < nblocks) ? partials[t] : 0;
    s[t] = v;
    __syncthreads();
    for (int off = 1; off < 1024; off <<= 1) {
        int u = (t >= off) ? s[t - off] : 0;
        __syncthreads();
        s[t] += u;
        __syncthreads();
    }
    if (t < nblocks) partials[t] = s[t] - v;   // exclusive prefix
}

__global__ __launch_bounds__(256)
void scan_phase3(const int* __restrict__ deg, const int* __restrict__ partials,
                 int* __restrict__ offsets, int* __restrict__ cursor, int n)
{
    __shared__ int s[256];
    int t = threadIdx.x;
    int i = blockIdx.x * 256 + t;
    int v = (i < n) ? deg[i] : 0;
    s[t] = v;
    __syncthreads();
    for (int off = 1; off < 256; off <<= 1) {
        int u = (t >= off) ? s[t - off] : 0;
        __syncthreads();
        s[t] += u;
        __syncthreads();
    }
    int excl = s[t] - v + partials[blockIdx.x];
    if (i < n) { offsets[i] = excl; cursor[i] = excl; }
    if (i == n - 1) offsets[n] = excl + v;
}

__global__ __launch_bounds__(256)
void scatter_kernel(const int* __restrict__ esrc, const int* __restrict__ edst,
                    int e_in, int e_tot, int* __restrict__ cursor,
                    int* __restrict__ csr_src)
{
    int e = blockIdx.x * 256 + threadIdx.x;
    if (e >= e_tot) return;
    int s, d;
    if (e < e_in) { s = esrc[e]; d = edst[e]; } else { s = e - e_in; d = s; }
    int pos = atomicAdd(&cursor[d], 1);
    csr_src[pos] = s;
}

// ---------------------------------------------------------------------------
// Fused attention, 2 edges per iteration (independent dep-chains for ILP).
// ---------------------------------------------------------------------------
template<int H>
__device__ __forceinline__ float edge_ex(float4 xlv, float4 xrv, float4 atv)
{
    float4 t = make_float4(xlv.x + xrv.x, xlv.y + xrv.y,
                           xlv.z + xrv.z, xlv.w + xrv.w);
    t.x = t.x > 0.f ? t.x : NEG_SLOPE * t.x;
    t.y = t.y > 0.f ? t.y : NEG_SLOPE * t.y;
    t.z = t.z > 0.f ? t.z : NEG_SLOPE * t.z;
    t.w = t.w > 0.f ? t.w : NEG_SLOPE * t.w;
    float p = t.x * atv.x + t.y * atv.y + t.z * atv.z + t.w * atv.w;
    p += __shfl_xor(p, 1);
    p += __shfl_xor(p, 2);
    p += __shfl_xor(p, 4);
    if (H == 1) {
        p += __shfl_xor(p, 8);
        p += __shfl_xor(p, 16);
    }
    return __expf(p);
}

template<int H>
__global__ __launch_bounds__(256)
void fused_attn(const float* __restrict__ xl, const float* __restrict__ xr,
                const float* __restrict__ att, const int* __restrict__ csr_src,
                const int* __restrict__ offsets, const float* __restrict__ bias,
                float* __restrict__ out, int n)
{
    int d = blockIdx.x * 8 + (threadIdx.x >> 5);
    if (d >= n) return;
    const int lane = threadIdx.x & 31;

    const float4 xrv = *reinterpret_cast<const float4*>(&xr[(size_t)d * 128 + lane * 4]);
    const float4 atv = *reinterpret_cast<const float4*>(&att[lane * 4]);

    const int start = offsets[d];
    const int end   = offsets[d + 1];

    float4 acc0 = make_float4(0.f, 0.f, 0.f, 0.f);
    float4 acc1 = make_float4(0.f, 0.f, 0.f, 0.f);
    float  den0 = 0.f, den1 = 0.f;

    for (int base = start; base < end; base += 32) {
        const int cnt = min(32, end - base);
        int sidx = (base + lane < end) ? csr_src[base + lane] : 0;
        int i = 0;
        for (; i + 2 <= cnt; i += 2) {
            int s0 = __shfl(sidx, i, 32);
            int s1 = __shfl(sidx, i + 1, 32);
            float4 x0 = *reinterpret_cast<const float4*>(&xl[(size_t)s0 * 128 + lane * 4]);
            float4 x1 = *reinterpret_cast<const float4*>(&xl[(size_t)s1 * 128 + lane * 4]);
            float ex0 = edge_ex<H>(x0, xrv, atv);
            float ex1 = edge_ex<H>(x1, xrv, atv);
            den0 += ex0;
            acc0.x = fmaf(x0.x, ex0, acc0.x);
            acc0.y = fmaf(x0.y, ex0, acc0.y);
            acc0.z = fmaf(x0.z, ex0, acc0.z);
            acc0.w = fmaf(x0.w, ex0, acc0.w);
            den1 += ex1;
            acc1.x = fmaf(x1.x, ex1, acc1.x);
            acc1.y = fmaf(x1.y, ex1, acc1.y);
            acc1.z = fmaf(x1.z, ex1, acc1.z);
            acc1.w = fmaf(x1.w, ex1, acc1.w);
        }
        if (i < cnt) {
            int s0 = __shfl(sidx, i, 32);
            float4 x0 = *reinterpret_cast<const float4*>(&xl[(size_t)s0 * 128 + lane * 4]);
            float ex0 = edge_ex<H>(x0, xrv, atv);
            den0 += ex0;
            acc0.x = fmaf(x0.x, ex0, acc0.x);
            acc0.y = fmaf(x0.y, ex0, acc0.y);
            acc0.z = fmaf(x0.z, ex0, acc0.z);
            acc0.w = fmaf(x0.w, ex0, acc0.w);
        }
    }

    const float inv = 1.f / (den0 + den1 + 1e-16f);
    const float4 bv = *reinterpret_cast<const float4*>(&bias[lane * 4]);
    float4 r = make_float4((acc0.x + acc1.x) * inv + bv.x,
                           (acc0.y + acc1.y) * inv + bv.y,
                           (acc0.z + acc1.z) * inv + bv.z,
                           (acc0.w + acc1.w) * inv + bv.w);
    *reinterpret_cast<float4*>(&out[(size_t)d * 128 + lane * 4]) = r;
}

// ---------------------------------------------------------------------------

extern "C" void kernel_launch(void* const* d_in, const int* in_sizes, int n_in,
                              void* d_out, int out_size, void* d_ws, size_t ws_size,
                              hipStream_t stream)
{
    const int*   edge  = (const int*)d_in[0];
    const float* embed = (const float*)d_in[1];
    const float* Wl1   = (const float*)d_in[2];
    const float* bl1   = (const float*)d_in[3];
    const float* Wr1   = (const float*)d_in[4];
    const float* br1   = (const float*)d_in[5];
    const float* att1  = (const float*)d_in[6];
    const float* b1    = (const float*)d_in[7];
    const float* Wl2   = (const float*)d_in[8];
    const float* bl2   = (const float*)d_in[9];
    const float* Wr2   = (const float*)d_in[10];
    const float* br2   = (const float*)d_in[11];
    const float* att2  = (const float*)d_in[12];
    const float* b2    = (const float*)d_in[13];

    const int e_in  = in_sizes[0] / 2;
    const int n     = in_sizes[1] / 128;
    const int e_tot = e_in + n;
    const int nblocks = (n + 255) / 256;

    float* ws   = (float*)d_ws;
    float* xl   = ws;                         // n*128 f
    float* xr   = xl + (size_t)n * 128;       // n*128 f
    float* h1   = xr + (size_t)n * 128;       // n*128 f
    int* csr_src  = (int*)(h1 + (size_t)n * 128);  // e_tot int
    int* offsets  = csr_src + e_tot;          // n+1 int
    int* cursor   = offsets + (n + 1);        // n int
    int* deg      = cursor + n;               // n int
    int* partials = deg + n;                  // nblocks int
    float* out    = (float*)d_out;

    const int* esrc = edge;
    const int* edst = edge + e_in;

    dim3 blk(256);
    const int gemm_blocks = (n + 31) / 32;
    const int node_blocks = (n + 7) / 8;
    const int edge_blocks = (e_tot + 255) / 256;

    // ---- CSR build (shared by both layers) ----
    hipMemsetAsync(deg, 0, (size_t)n * sizeof(int), stream);
    deg_count<<<edge_blocks, blk, 0, stream>>>(edst, e_in, e_tot, deg);
    scan_phase1<<<nblocks, blk, 0, stream>>>(deg, partials, n);
    scan_phase2<<<1, 1024, 0, stream>>>(partials, nblocks);
    scan_phase3<<<nblocks, blk, 0, stream>>>(deg, partials, offsets, cursor, n);
    scatter_kernel<<<edge_blocks, blk, 0, stream>>>(esrc, edst, e_in, e_tot, cursor, csr_src);

    // ---- layer 1 (4 heads x 32 ch) ----
    gemm_dual<false><<<gemm_blocks, blk, 0, stream>>>(embed, Wl1, bl1, Wr1, br1, xl, xr, n);
    fused_attn<4><<<node_blocks, blk, 0, stream>>>(xl, xr, att1, csr_src, offsets, b1, h1, n);

    // ---- layer 2 (1 head x 128 ch); relu folded into GEMM x-load ----
    gemm_dual<true><<<gemm_blocks, blk, 0, stream>>>(h1, Wl2, bl2, Wr2, br2, xl, xr, n);
    fused_attn<1><<<node_blocks, blk, 0, stream>>>(xl, xr, att2, csr_src, offsets, b2, out, n);
}